// Round 12
// baseline (30.254 us; speedup 1.0000x reference)
//
#include <hip/hip_runtime.h>
#include <math.h>

#define NV 65536
#define NE 4096
#define NP 4096
#define NT 512
#define SENTF 1000000000.0f
#define BIGF 1e30f

// ---------------- wave(64) reduction helpers ----------------
__device__ __forceinline__ float waveMinF(float v) {
    #pragma unroll
    for (int o = 32; o; o >>= 1) v = fminf(v, __shfl_xor(v, o, 64));
    return v;
}
__device__ __forceinline__ float waveMaxF(float v) {
    #pragma unroll
    for (int o = 32; o; o >>= 1) v = fmaxf(v, __shfl_xor(v, o, 64));
    return v;
}
__device__ __forceinline__ int waveSumI(int v) {
    #pragma unroll
    for (int o = 32; o; o >>= 1) v += __shfl_xor(v, o, 64);
    return v;
}
__device__ __forceinline__ int waveMinI(int v) {
    #pragma unroll
    for (int o = 32; o; o >>= 1) v = min(v, __shfl_xor(v, o, 64));
    return v;
}

// ---------------- kernel 1: per-edge params + table repack (validated) ----------------
__global__ void prep_kernel(const float* __restrict__ verts,
                            const int*   __restrict__ edges,
                            const float* __restrict__ tab,
                            float*  __restrict__ ea,   float*  __restrict__ eb,
                            float4* __restrict__ pk14, float4* __restrict__ pk4,
                            float4* __restrict__ tb4) {
    int e = blockIdx.x * blockDim.x + threadIdx.x;
    if (e < NT) {
        const float* r = tab + 7 * e;
        tb4[e] = make_float4(r[3], r[4], r[5], r[6]);
    }
    if (e >= NE) return;
    int i0 = edges[2 * e + 0];
    int i1 = edges[2 * e + 1];
    float x0 = verts[3 * i0 + 0], y0 = verts[3 * i0 + 1];
    float x1 = verts[3 * i1 + 0], y1 = verts[3 * i1 + 1];
    float a = (y0 - y1) / (x0 - x1);
    float b = y0 - a * x0;
    ea[e] = a; eb[e] = b;
    pk14[e] = make_float4(fminf(x0, x1), fmaxf(x0, x1), a, b);        // phase-1 record
    pk4[e]  = make_float4(fminf(y0, y1), fmaxf(y0, y1), 1.0f / a, b); // phase-2 record
}

// ---------------- kernel 2a: phase 1 only, 4-wide batched early exit ----------------
// 1024 blocks x 256 thr = 4 waves, one point each. Batch of 256 edges per
// exit-check (4 independent loads in flight) -> serial chain cut 4x.
__global__ __launch_bounds__(256) void pointA_kernel(
        const float*  __restrict__ verts,
        const int*    __restrict__ listAll,
        const float*  __restrict__ ea, const float* __restrict__ eb,
        const float4* __restrict__ pk14,
        float* __restrict__ cyArr, float* __restrict__ l1Arr,
        float* __restrict__ pxArr) {
    const int lane = threadIdx.x & 63;
    const int w    = threadIdx.x >> 6;
    const int p    = blockIdx.x * 4 + w;

    int   vi = listAll[p];
    float px = verts[3 * vi + 0];
    float py = verts[3 * vi + 1];

    int   idxSel = NE;
    float aSel = 0.f, bSel = 0.f;
    for (int it = 0; it < NE / 256; ++it) {
        int e0 = it * 256 + lane;
        float4 qa = pk14[e0];
        float4 qb = pk14[e0 + 64];
        float4 qc = pk14[e0 + 128];
        float4 qd = pk14[e0 + 192];
        bool h0 = (px > qa.x) && (px < qa.y);
        bool h1 = (px > qb.x) && (px < qb.y);
        bool h2 = (px > qc.x) && (px < qc.y);
        bool h3 = (px > qd.x) && (px < qd.y);
        // lane-local first hit (ascending priority: e0 < e0+64 < e0+128 < e0+192)
        int il = NE; float as = 0.f, bs = 0.f;
        if (h3) { il = e0 + 192; as = qd.z; bs = qd.w; }
        if (h2) { il = e0 + 128; as = qc.z; bs = qc.w; }
        if (h1) { il = e0 + 64;  as = qb.z; bs = qb.w; }
        if (h0) { il = e0;       as = qa.z; bs = qa.w; }
        bool any4 = h0 | h1 | h2 | h3;
        if (any4) { idxSel = il; aSel = as; bSel = bs; }
        if (__any(any4)) break;   // first batch with a hit contains the global first hit
    }
    int mi = waveMinI(idxSel);
    float a_ = __shfl(aSel, mi & 63, 64);
    float b_ = __shfl(bSel, mi & 63, 64);
    if (mi >= NE) { a_ = ea[NE - 1]; b_ = eb[NE - 1]; }   // no straddling edge

    float exposeY = a_ * px + b_;                 // identical arithmetic to reference
    if (lane == 0) {
        cyArr[p] = 0.5f * (py + exposeY);
        l1Arr[p] = fabsf(py - exposeY);
        pxArr[p] = px;
    }
}

// ---------------- kernel 2b: phase 2 + folds + table (R7-validated body) ----------------
// 1024 blocks x 256 thr = 4 waves. Wave w covers edge quarter for ALL 4 points.
__global__ __launch_bounds__(256) void pointB_kernel(
        const float4* __restrict__ pk4,  const float4* __restrict__ tb4,
        const float*  __restrict__ cyArr, const float* __restrict__ l1Arr,
        const float*  __restrict__ pxArr,
        float* __restrict__ mOut, int* __restrict__ vOut) {
    __shared__ float sQ[4][4][6];   // [wave][point][stat]
    __shared__ float sF[4][6];      // folded per point
    __shared__ float sL2[4];
    __shared__ int   sVal[4];

    const int tid  = threadIdx.x;
    const int lane = tid & 63;
    const int w    = tid >> 6;       // 0..3
    const int pBase = blockIdx.x * 4;

    float cyv[4], cxv[4];
    #pragma unroll
    for (int p = 0; p < 4; ++p) {
        cyv[p] = cyArr[pBase + p];
        cxv[p] = pxArr[pBase + p];
    }

    // ---- phase 2: per-point accumulators, each edge load reused x4 (validated) ----
    float mx[4], mn[4], xs[4], xf[4];
    int   nC[4], hh[4];               // hh = hasS | hasI<<16
    #pragma unroll
    for (int p = 0; p < 4; ++p) {
        mx[p] = -SENTF; mn[p] = SENTF; xs[p] = SENTF; xf[p] = -SENTF;
        nC[p] = 0; hh[p] = 0;
    }

    #pragma unroll 4
    for (int it = 0; it < 16; ++it) {
        float4 q = pk4[w * 1024 + it * 64 + lane];   // (ymn, ymx, 1/a, b)
        #pragma unroll
        for (int p = 0; p < 4; ++p) {
            float cy = cyv[p], cx = cxv[p];
            bool  c  = (cy > q.x) && (cy < q.y);
            float xi = (cy - q.w) * q.z;             // identical arithmetic to validated path
            nC[p] += c ? 1 : 0;
            mx[p] = fmaxf(mx[p], c ? xi : -SENTF);
            mn[p] = fminf(mn[p], c ? xi :  SENTF);
            bool sp  = c && (xi >= cx);
            bool in_ = c && (xi <  cx);
            xs[p] = fminf(xs[p], sp  ? xi :  SENTF);
            xf[p] = fmaxf(xf[p], in_ ? xi : -SENTF);
            hh[p] |= (sp ? 1 : 0) | (in_ ? 0x10000 : 0);
        }
    }

    // ---- wave-reduce each point's stats, lane0 -> LDS (validated) ----
    #pragma unroll
    for (int p = 0; p < 4; ++p) {
        float a0 = waveMaxF(mx[p]);
        float a1 = waveMinF(mn[p]);
        float a2 = waveMinF(xs[p]);
        float a3 = waveMaxF(xf[p]);
        int   a4 = waveSumI(nC[p]);
        int   a5 = waveSumI(hh[p]);   // fields <= 64 each, no carry
        if (lane == 0) {
            sQ[w][p][0] = a0; sQ[w][p][1] = a1;
            sQ[w][p][2] = a2; sQ[w][p][3] = a3;
            sQ[w][p][4] = __int_as_float(a4);
            sQ[w][p][5] = __int_as_float(a5);
        }
    }
    __syncthreads();

    // ---- fold 4 waves: 24 threads, one (point, stat) each (validated) ----
    if (tid < 24) {
        int p = tid & 3, s = tid >> 2;   // s in 0..5
        if (s == 0)      sF[p][0] = fmaxf(fmaxf(sQ[0][p][0], sQ[1][p][0]), fmaxf(sQ[2][p][0], sQ[3][p][0]));
        else if (s == 1) sF[p][1] = fminf(fminf(sQ[0][p][1], sQ[1][p][1]), fminf(sQ[2][p][1], sQ[3][p][1]));
        else if (s == 2) sF[p][2] = fminf(fminf(sQ[0][p][2], sQ[1][p][2]), fminf(sQ[2][p][2], sQ[3][p][2]));
        else if (s == 3) sF[p][3] = fmaxf(fmaxf(sQ[0][p][3], sQ[1][p][3]), fmaxf(sQ[2][p][3], sQ[3][p][3]));
        else if (s == 4) sF[p][4] = __int_as_float(__float_as_int(sQ[0][p][4]) + __float_as_int(sQ[1][p][4])
                                                 + __float_as_int(sQ[2][p][4]) + __float_as_int(sQ[3][p][4]));
        else             sF[p][5] = __int_as_float(__float_as_int(sQ[0][p][5]) + __float_as_int(sQ[1][p][5])
                                                 + __float_as_int(sQ[2][p][5]) + __float_as_int(sQ[3][p][5]));
    }
    __syncthreads();

    // ---- per-point finish: valid, L2 (validated) ----
    if (tid < 4) {
        int n  = __float_as_int(sF[tid][4]);
        int hc = __float_as_int(sF[tid][5]);
        int hS = hc & 0xFFFF, hI = hc >> 16;
        bool valid = (n == 2) || ((n > 2) && (hS > 0) && (hI > 0));
        float dx = (n == 2) ? (sF[tid][0] - sF[tid][1]) : (sF[tid][2] - sF[tid][3]);
        sL2[tid]  = fabsf(dx);
        sVal[tid] = valid ? 1 : 0;
    }
    __syncthreads();

    // ---- table min: wave w -> point w (validated float4 path) ----
    {
        float L1v = l1Arr[pBase + w], L2v = sL2[w];
        float d1  = fabsf(cyv[w] - 1.0f);
        float d2  = fabsf(cxv[w] - 1.0f);
        float pm = INFINITY;
        #pragma unroll
        for (int kk = 0; kk < NT / 64; ++kk) {
            float4 r = tb4[kk * 64 + lane];
            float al = fabsf(L1v - r.x) + fabsf(L2v - r.y) +
                       fabsf(d1 - r.z) + fabsf(d2 - r.w);
            pm = fminf(pm, al);
        }
        pm = waveMinF(pm);
        if (lane == 0) {
            mOut[pBase + w] = sVal[w] ? pm : BIGF;
            vOut[pBase + w] = sVal[w];
        }
    }
}

// ---------------- kernel 3: cummin + masked sum (validated) ----------------
__global__ __launch_bounds__(1024) void scan_kernel(const float* __restrict__ m,
                                                    const int*   __restrict__ valid,
                                                    float* __restrict__ out) {
    __shared__ float wAgg[16];
    __shared__ float wSum[16];
    int t = threadIdx.x;
    int lane = t & 63, wid = t >> 6;

    float v[4]; int vl[4];
    #pragma unroll
    for (int j = 0; j < 4; j++) { v[j] = m[4 * t + j]; vl[j] = valid[4 * t + j]; }
    float cmin = fminf(fminf(v[0], v[1]), fminf(v[2], v[3]));

    float inc = cmin;
    #pragma unroll
    for (int o = 1; o < 64; o <<= 1) {
        float u = __shfl_up(inc, o, 64);
        if (lane >= o) inc = fminf(inc, u);
    }
    if (lane == 63) wAgg[wid] = inc;
    __syncthreads();

    float wavePrefix = INFINITY;
    for (int i = 0; i < wid; i++) wavePrefix = fminf(wavePrefix, wAgg[i]);
    float excl = __shfl_up(inc, 1, 64);
    if (lane == 0) excl = INFINITY;
    float run = fminf(wavePrefix, excl);

    float sum = 0.0f;
    #pragma unroll
    for (int j = 0; j < 4; j++) {
        run = fminf(run, v[j]);
        if (vl[j]) sum += run;
    }
    #pragma unroll
    for (int o = 32; o; o >>= 1) sum += __shfl_xor(sum, o, 64);
    if (lane == 0) wSum[wid] = sum;
    __syncthreads();
    if (t == 0) {
        float s = 0.0f;
        for (int i = 0; i < 16; i++) s += wSum[i];
        out[0] = s;
    }
}

extern "C" void kernel_launch(void* const* d_in, const int* in_sizes, int n_in,
                              void* d_out, int out_size, void* d_ws, size_t ws_size,
                              hipStream_t stream) {
    const float* verts   = (const float*)d_in[0];
    const float* tab     = (const float*)d_in[1];
    const int*   edges   = (const int*)d_in[2];
    const int*   listAll = (const int*)d_in[3];

    char* ws = (char*)d_ws;
    float4* pk4  = (float4*)ws;                   ws += NE * sizeof(float4);
    float4* pk14 = (float4*)ws;                   ws += NE * sizeof(float4);
    float4* tb4  = (float4*)ws;                   ws += NT * sizeof(float4);
    float*  ea   = (float*)ws;                    ws += NE * sizeof(float);
    float*  eb   = (float*)ws;                    ws += NE * sizeof(float);
    float*  cyArr= (float*)ws;                    ws += NP * sizeof(float);
    float*  l1Arr= (float*)ws;                    ws += NP * sizeof(float);
    float*  pxArr= (float*)ws;                    ws += NP * sizeof(float);
    float*  mArr = (float*)ws;                    ws += NP * sizeof(float);
    int*    vArr = (int*)ws;

    prep_kernel<<<(NE + 255) / 256, 256, 0, stream>>>(verts, edges, tab,
                                                      ea, eb, pk14, pk4, tb4);
    pointA_kernel<<<NP / 4, 256, 0, stream>>>(verts, listAll, ea, eb, pk14,
                                              cyArr, l1Arr, pxArr);
    pointB_kernel<<<NP / 4, 256, 0, stream>>>(pk4, tb4, cyArr, l1Arr, pxArr,
                                              mArr, vArr);
    scan_kernel<<<1, 1024, 0, stream>>>(mArr, vArr, (float*)d_out);
}

// Round 13
// 27.871 us; speedup vs baseline: 1.0855x; 1.0855x over previous
//
#include <hip/hip_runtime.h>
#include <math.h>

#define NV 65536
#define NE 4096
#define NP 4096
#define NT 512
#define NB 32              // y-buckets
#define CAP 4096           // per-bucket capacity; cnt <= NE always, no overflow possible
#define SENTF 1000000000.0f
#define BIGF 1e30f

// ---------------- wave(64) reduction helpers ----------------
__device__ __forceinline__ float waveMinF(float v) {
    #pragma unroll
    for (int o = 32; o; o >>= 1) v = fminf(v, __shfl_xor(v, o, 64));
    return v;
}
__device__ __forceinline__ float waveMaxF(float v) {
    #pragma unroll
    for (int o = 32; o; o >>= 1) v = fmaxf(v, __shfl_xor(v, o, 64));
    return v;
}
__device__ __forceinline__ int waveSumI(int v) {
    #pragma unroll
    for (int o = 32; o; o >>= 1) v += __shfl_xor(v, o, 64);
    return v;
}
__device__ __forceinline__ int waveMinI(int v) {
    #pragma unroll
    for (int o = 32; o; o >>= 1) v = min(v, __shfl_xor(v, o, 64));
    return v;
}

// ---------------- kernel 1: buckets (blocks 0..31) + pk14 (32..35) + table (36) ----------------
// Bucket block b: recomputes all 4096 edge records locally (no inter-block dep),
// selects edges overlapping bucket b, ORDERED ballot-free compaction via shfl
// prefix scan. No atomics, no fences, no memset needed.
__global__ __launch_bounds__(1024) void prep_kernel(
        const float* __restrict__ verts,
        const int*   __restrict__ edges,
        const float* __restrict__ tab,
        float4* __restrict__ pk14, float4* __restrict__ tb4,
        float4* __restrict__ bk4,  int* __restrict__ cnt) {
    const int blk = blockIdx.x;
    const int tid = threadIdx.x;

    if (blk < NB) {
        __shared__ int sWT[16];
        const int lane = tid & 63;
        const int wv   = tid >> 6;

        // 4 consecutive edges per thread (keeps edge order under prefix scan)
        float4 rec[4];
        int    flg[4];
        int    c = 0;
        #pragma unroll
        for (int j = 0; j < 4; ++j) {
            int e  = tid * 4 + j;
            int i0 = edges[2 * e + 0];
            int i1 = edges[2 * e + 1];
            float x0 = verts[3 * i0 + 0], y0 = verts[3 * i0 + 1];
            float x1 = verts[3 * i1 + 0], y1 = verts[3 * i1 + 1];
            float a = (y0 - y1) / (x0 - x1);
            float b = y0 - a * x0;
            float ymn = fminf(y0, y1), ymx = fmaxf(y0, y1);
            rec[j] = make_float4(ymn, ymx, 1.0f / a, b);   // validated phase-2 record
            int b0 = (int)fminf(fmaxf(ymn * (float)NB, 0.f), (float)(NB - 1));
            int b1 = (int)fminf(fmaxf(ymx * (float)NB, 0.f), (float)(NB - 1));
            flg[j] = (blk >= b0) && (blk <= b1);
            c += flg[j];
        }
        // inclusive wave scan of per-thread counts
        int inc = c;
        #pragma unroll
        for (int o = 1; o < 64; o <<= 1) {
            int u = __shfl_up(inc, o, 64);
            if (lane >= o) inc += u;
        }
        if (lane == 63) sWT[wv] = inc;
        __syncthreads();
        int base = 0;
        for (int i = 0; i < wv; ++i) base += sWT[i];
        int off = base + inc - c;                    // exclusive offset, edge-ordered
        float4* dst = bk4 + (size_t)blk * CAP;
        #pragma unroll
        for (int j = 0; j < 4; ++j)
            if (flg[j]) dst[off++] = rec[j];
        if (tid == 0) {
            int tot = 0;
            for (int i = 0; i < 16; ++i) tot += sWT[i];
            cnt[blk] = tot;
        }
    } else if (blk < NB + 4) {
        int e  = (blk - NB) * 1024 + tid;
        int i0 = edges[2 * e + 0];
        int i1 = edges[2 * e + 1];
        float x0 = verts[3 * i0 + 0], y0 = verts[3 * i0 + 1];
        float x1 = verts[3 * i1 + 0], y1 = verts[3 * i1 + 1];
        float a = (y0 - y1) / (x0 - x1);
        float b = y0 - a * x0;
        pk14[e] = make_float4(fminf(x0, x1), fmaxf(x0, x1), a, b);   // phase-1 record
    } else {
        if (tid < NT) {
            const float* r = tab + 7 * tid;
            tb4[tid] = make_float4(r[3], r[4], r[5], r[6]);
        }
    }
}

// ---------------- kernel 2: 4 independent waves/block, bucket-pruned phase 2 ----------------
__global__ __launch_bounds__(256) void point_kernel(
        const float*  __restrict__ verts,
        const int*    __restrict__ listAll,
        const float4* __restrict__ pk14, const float4* __restrict__ bk4,
        const int*    __restrict__ cnt,  const float4* __restrict__ tb4,
        float* __restrict__ mOut, int* __restrict__ vOut) {
    const int lane = threadIdx.x & 63;
    const int w    = threadIdx.x >> 6;
    const int p    = blockIdx.x * 4 + w;

    int   vi = listAll[p];
    float px = verts[3 * vi + 0];
    float py = verts[3 * vi + 1];

    // ---- phase 1: 4-wide batched early-exit (R12-validated, bit-exact) ----
    int   idxSel = NE;
    float aSel = 0.f, bSel = 0.f;
    for (int it = 0; it < NE / 256; ++it) {
        int e0 = it * 256 + lane;
        float4 qa = pk14[e0];
        float4 qb = pk14[e0 + 64];
        float4 qc = pk14[e0 + 128];
        float4 qd = pk14[e0 + 192];
        bool h0 = (px > qa.x) && (px < qa.y);
        bool h1 = (px > qb.x) && (px < qb.y);
        bool h2 = (px > qc.x) && (px < qc.y);
        bool h3 = (px > qd.x) && (px < qd.y);
        int il = NE; float as = 0.f, bs = 0.f;
        if (h3) { il = e0 + 192; as = qd.z; bs = qd.w; }
        if (h2) { il = e0 + 128; as = qc.z; bs = qc.w; }
        if (h1) { il = e0 + 64;  as = qb.z; bs = qb.w; }
        if (h0) { il = e0;       as = qa.z; bs = qa.w; }
        bool any4 = h0 | h1 | h2 | h3;
        if (any4) { idxSel = il; aSel = as; bSel = bs; }
        if (__any(any4)) break;
    }
    int mi = waveMinI(idxSel);
    float a_ = __shfl(aSel, mi & 63, 64);
    float b_ = __shfl(bSel, mi & 63, 64);
    if (mi >= NE) {                       // no straddling edge -> idx = NE-1
        float4 qf = pk14[NE - 1];
        a_ = qf.z; b_ = qf.w;
    }
    float exposeY = a_ * px + b_;         // identical arithmetic to reference
    float L1 = fabsf(py - exposeY);
    float cy = 0.5f * (py + exposeY);
    float cx = px;

    // ---- phase 2: scan only bucket(cy) (R9-validated body) ----
    float kf = fminf(fmaxf(cy * (float)NB, 0.f), (float)(NB - 1));  // NaN-safe clamp
    int   k  = (int)kf;                   // wave-uniform
    int   len = cnt[k];
    const float4* bl = bk4 + (size_t)k * CAP;

    int   nAcc = 0, hasS = 0, hasI = 0;
    float xallmx = -SENTF, xallmn = SENTF;
    float xs = SENTF, xinf = -SENTF;
    for (int i = lane; i < len; i += 64) {
        float4 q = bl[i];                  // (ymn, ymx, 1/a, b)
        bool  c  = (cy > q.x) && (cy < q.y);
        float xi = (cy - q.w) * q.z;       // identical arithmetic to validated path
        nAcc += c ? 1 : 0;
        xallmx = fmaxf(xallmx, c ? xi : -SENTF);
        xallmn = fminf(xallmn, c ? xi :  SENTF);
        bool sp  = c && (xi >= cx);
        bool in_ = c && (xi <  cx);
        xs   = fminf(xs,   sp  ? xi :  SENTF);
        xinf = fmaxf(xinf, in_ ? xi : -SENTF);
        hasS |= sp ? 1 : 0;
        hasI |= in_ ? 1 : 0;
    }
    int packed = nAcc | (hasS << 16) | (hasI << 24);   // n<=4096 (13b), hasS/I sums <=64
    packed = waveSumI(packed);
    xallmx = waveMaxF(xallmx);
    xallmn = waveMinF(xallmn);
    xs     = waveMinF(xs);
    xinf   = waveMaxF(xinf);
    int n  = packed & 0xFFFF;
    int hS = (packed >> 16) & 0xFF;
    int hI = (packed >> 24) & 0xFF;

    bool valid = (n == 2) || ((n > 2) && (hS > 0) && (hI > 0));
    float dx = (n == 2) ? (xallmx - xallmn) : (xs - xinf);
    float L2 = fabsf(dx);
    float d1 = fabsf(cy - 1.0f);
    float d2 = fabsf(px - 1.0f);

    // ---- table min (validated float4 path) ----
    float pm = INFINITY;
    #pragma unroll
    for (int kk = 0; kk < NT / 64; ++kk) {
        float4 r = tb4[kk * 64 + lane];
        float al = fabsf(L1 - r.x) + fabsf(L2 - r.y) +
                   fabsf(d1 - r.z) + fabsf(d2 - r.w);
        pm = fminf(pm, al);
    }
    pm = waveMinF(pm);

    if (lane == 0) {
        mOut[p] = valid ? pm : BIGF;
        vOut[p] = valid ? 1 : 0;
    }
}

// ---------------- kernel 3: cummin + masked sum (validated) ----------------
__global__ __launch_bounds__(1024) void scan_kernel(const float* __restrict__ m,
                                                    const int*   __restrict__ valid,
                                                    float* __restrict__ out) {
    __shared__ float wAgg[16];
    __shared__ float wSum[16];
    int t = threadIdx.x;
    int lane = t & 63, wid = t >> 6;

    float v[4]; int vl[4];
    #pragma unroll
    for (int j = 0; j < 4; j++) { v[j] = m[4 * t + j]; vl[j] = valid[4 * t + j]; }
    float cmin = fminf(fminf(v[0], v[1]), fminf(v[2], v[3]));

    float inc = cmin;
    #pragma unroll
    for (int o = 1; o < 64; o <<= 1) {
        float u = __shfl_up(inc, o, 64);
        if (lane >= o) inc = fminf(inc, u);
    }
    if (lane == 63) wAgg[wid] = inc;
    __syncthreads();

    float wavePrefix = INFINITY;
    for (int i = 0; i < wid; i++) wavePrefix = fminf(wavePrefix, wAgg[i]);
    float excl = __shfl_up(inc, 1, 64);
    if (lane == 0) excl = INFINITY;
    float run = fminf(wavePrefix, excl);

    float sum = 0.0f;
    #pragma unroll
    for (int j = 0; j < 4; j++) {
        run = fminf(run, v[j]);
        if (vl[j]) sum += run;
    }
    #pragma unroll
    for (int o = 32; o; o >>= 1) sum += __shfl_xor(sum, o, 64);
    if (lane == 0) wSum[wid] = sum;
    __syncthreads();
    if (t == 0) {
        float s = 0.0f;
        for (int i = 0; i < 16; i++) s += wSum[i];
        out[0] = s;
    }
}

extern "C" void kernel_launch(void* const* d_in, const int* in_sizes, int n_in,
                              void* d_out, int out_size, void* d_ws, size_t ws_size,
                              hipStream_t stream) {
    const float* verts   = (const float*)d_in[0];
    const float* tab     = (const float*)d_in[1];
    const int*   edges   = (const int*)d_in[2];
    const int*   listAll = (const int*)d_in[3];

    char* ws = (char*)d_ws;
    float4* bk4  = (float4*)ws;                   ws += (size_t)NB * CAP * sizeof(float4); // 2 MB
    float4* pk14 = (float4*)ws;                   ws += NE * sizeof(float4);
    float4* tb4  = (float4*)ws;                   ws += NT * sizeof(float4);
    float*  mArr = (float*)ws;                    ws += NP * sizeof(float);
    int*    vArr = (int*)ws;                      ws += NP * sizeof(int);
    int*    cnt  = (int*)ws;

    prep_kernel<<<NB + 5, 1024, 0, stream>>>(verts, edges, tab, pk14, tb4, bk4, cnt);
    point_kernel<<<NP / 4, 256, 0, stream>>>(verts, listAll, pk14, bk4, cnt, tb4,
                                             mArr, vArr);
    scan_kernel<<<1, 1024, 0, stream>>>(mArr, vArr, (float*)d_out);
}